// Round 6
// baseline (523.542 us; speedup 1.0000x reference)
//
#include <hip/hip_runtime.h>
#include <hip/hip_bf16.h>
#include <stdint.h>
#include <math.h>

// FixedPointHGRNAttention on MI355X — r9: r8's 4-phase quadrant schedule with
// PREFETCH DISTANCE 1.5 K-TILES (stage tile t+2 into the current slot as each
// half-region's last reader retires). r8 post-mortem: r7 (2-phase) and r8
// (4-phase) tie at MfmaUtil 36% because both stage t+1 during t — issue->wait
// slack 2-3 phases (~500 cyc) < HBM latency (~900 cyc); each of 3 wait points
// stalls ~900 cyc = the whole 2900 cyc/tile gap vs the m201 template (62%).
// Steady-state waits: end-ph0 vmcnt(10), end-ph1 vmcnt(12), end-ph3 vmcnt(12)
// (exact queue accounting in kloop256 comments); tails tighten 8/4/2/0.
// 256x256 tile, BK=64, 8 waves, 128 KiB LDS (2 slots x {AL,AH,BL,BH}).
// Spill-safe flat acc[8][4], all indices compile-time (rule #20).
// XOR-swizzled LDS via pre-swizzled global_load_lds source.
// XCD 4m x 8n co-resident supertiles (FETCH 406->148 MB since r7).
//
// ws layout (88 MiB needed):
//   [0,   32M)  XB  bf16 [8192][2048]       -> later Hb (aliased)
//   [32M, 56M)  WT  bf16 [3][2048][2048]    (dead after gemm_gates)
//       [32M,33M) Pc, [33M,34M) Sc  (scan carries, overlay dead WT)
//       [34M,42M) WOB bf16 [2048][2048]     (w_o, written after scan)
//   [56M, 88M)  Ib  bf16 [8192][2048]       -> later OS (aliased)
// d_out scratch (64 MiB, overwritten by gemm_out):
//   Gb = d_out[0,32M)  (swish(g)*gnw*s_o), Fb = d_out[32M,64M) (sigmoid f)

#define BATCH 4
#define SEQ   2048
#define DIM   2048
#define MROWS (BATCH*SEQ)   // 8192
#define TCH   64
#define NCH   (SEQ/TCH)     // 32

// GEMM geometry: 256x256 tile, BK=64, 8 waves (2 row-bands x 4 col-bands)
#define GBM 256
#define GBN 256
#define GBK 64
#define GNT (DIM/GBK)        // 32 K-tiles
#define HALF 8192            // u16 per half-tile (128 rows x 64 cols)
#define SLOT (4*HALF)        // u16 per dbuf slot: {AL, AH, BL, BH}

typedef unsigned short u16;
typedef __attribute__((ext_vector_type(8))) short short8;
typedef __attribute__((ext_vector_type(4))) float f32x4;

static __device__ __forceinline__ u16 f2bf_rne(float x) {
  uint32_t u = __float_as_uint(x);
  u += 0x7FFFu + ((u >> 16) & 1u);
  return (u16)(u >> 16);
}
static __device__ __forceinline__ float bf2f(u16 h) {
  return __uint_as_float(((uint32_t)h) << 16);
}

static __device__ __forceinline__ void gl2lds16(const void* g, void* l) {
  __builtin_amdgcn_global_load_lds((const __attribute__((address_space(1))) void*)g,
                                   (__attribute__((address_space(3))) void*)l,
                                   16, 0, 0);
}

// ---------- diagnostic path (ws too small): absmax ~= ws_size MiB
__global__ __launch_bounds__(256) void diag_ws(float* __restrict__ out, float val) {
  size_t i = ((size_t)blockIdx.x * 256 + threadIdx.x) * 8;
#pragma unroll
  for (int j = 0; j < 8; j++) out[i + j] = val;
}

// ---------- P1: x -> to_fixed -> bf16 (RNE)
__global__ __launch_bounds__(256) void prep_x(const float* __restrict__ x,
                                              u16* __restrict__ XB) {
  size_t i = ((size_t)blockIdx.x * 256 + threadIdx.x) * 4;
  float4 v = *(const float4*)(x + i);
  float q[4] = {v.x, v.y, v.z, v.w};
  u16 hh[4];
#pragma unroll
  for (int j = 0; j < 4; j++) {
    float xq = rintf(q[j] * 256.0f) * 0.00390625f;
    hh[j] = f2bf_rne(xq);
  }
  *(uint2*)(XB + i) = make_uint2((uint32_t)hh[0] | ((uint32_t)hh[1] << 16),
                                 (uint32_t)hh[2] | ((uint32_t)hh[3] << 16));
}

// ---------- P2a: transpose w_i/w_f/w_g (DxE ternary) -> WT[g][e][d] bf16
__global__ void prep_wT(const float* __restrict__ w_i, const float* __restrict__ w_f,
                        const float* __restrict__ w_g, u16* __restrict__ WT) {
  __shared__ u16 tile[32][33];
  const int g = blockIdx.z;
  const float* __restrict__ w = (g == 0) ? w_i : (g == 1) ? w_f : w_g;
  u16* __restrict__ outp = WT + (size_t)g * DIM * DIM;
  const int d0 = blockIdx.x * 32;
  const int e0 = blockIdx.y * 32;
  const int tx = threadIdx.x;
  const int ty = threadIdx.y;
  for (int ii = ty; ii < 32; ii += 8)
    tile[ii][tx] = f2bf_rne(w[(size_t)(d0 + ii) * DIM + e0 + tx]);
  __syncthreads();
  for (int ii = ty; ii < 32; ii += 8)
    outp[(size_t)(e0 + ii) * DIM + d0 + tx] = tile[tx][ii];
}

// ---------- P2b: w_o [O][E] -> bf16 (already B^T layout)
__global__ __launch_bounds__(256) void prep_wo(const float* __restrict__ w, u16* __restrict__ WB) {
  size_t i = ((size_t)blockIdx.x * 256 + threadIdx.x) * 4;
  float4 v = *(const float4*)(w + i);
  *(uint2*)(WB + i) = make_uint2((uint32_t)f2bf_rne(v.x) | ((uint32_t)f2bf_rne(v.y) << 16),
                                 (uint32_t)f2bf_rne(v.z) | ((uint32_t)f2bf_rne(v.w) << 16));
}

// ---------- staging: one 128x64 half-tile, 2 gl2lds16/thread, linear LDS dest,
// global source pre-swizzled: LDS chunk c holds global (row=c>>3, (c&7)^(row&7)).
static __device__ __forceinline__ void stage_half(const u16* g, u16* l, int tid) {
  gl2lds16(g, l + (size_t)tid * 8);
  gl2lds16(g + (size_t)64 * DIM, l + (size_t)(tid + 512) * 8);
}

// ---------- K-loop: 4 quadrant-phases/K-tile, 2 slots, prefetch dist = 2 tiles.
// Tile t lives in slot t&1; tile t+2 (same slot) is staged DURING tile t, into
// each half-region right after its last reader's barrier:
//   ph1(t): stage AL(t+2), BL(t+2)   [AL,BL read only in ph0(t)]
//   ph2(t): stage BH(t+2)            [BH read in ph1(t)]
//   ph3(t): stage AH(t+2)            [AH read in ph2(t)]
// Issue->wait distance 6-7 phases (~1100-1500 cyc) > HBM ~900 cyc.
// Queue accounting (2 loads/half, issue order ...ph1(t-1):4, ph2(t-1):2,
// ph3(t-1):2, ph1(t):4, ph2(t):2, ph3(t):2...):
//   end-ph0(t): need BH(t) [ph2(t-2)]; newer: AH(t)2 + tile(t+1)8 -> vmcnt(10)
//               (t=GNT-1: only AH(t)2 -> vmcnt(2))
//   end-ph1(t): need AH(t) [ph3(t-2)]; newer: tile(t+1)8 + ph1(t)4 -> vmcnt(12)
//               (t=GNT-2: 8 -> vmcnt(8); t=GNT-1: 0 -> vmcnt(0))
//   end-ph3(t): need AL,BL(t+1) [ph1(t-1)]; newer: BH,AH(t+1)4 + tile(t+2)8
//               -> vmcnt(12)  (t=GNT-2: 4 -> vmcnt(4); t=GNT-1: skip)
static __device__ __forceinline__ void kloop256(const u16* __restrict__ Ag,
                                                const u16* __restrict__ Bg,
                                                u16* lds, f32x4 (&acc)[8][4]) {
  const int tid = threadIdx.x;
  const int lane16 = tid & 15;
  const int quad = (tid & 63) >> 4;
  const int wid = tid >> 6;
  const int wR = wid >> 2;      // 0..1: 64-row band within each 128-row half
  const int wC = wid & 3;       // 0..3: 32-col band within each 128-col half

  // staging source: chunk c = tid + j*512 -> row=c>>3, col-chunk=(c&7)^(row&7)
  const int rowS = tid >> 3;                     // 0..63 (j adds 64; row&7 invariant)
  const int ccS = ((tid & 7) ^ (rowS & 7)) * 8;
  const u16* gA = Ag + (size_t)rowS * DIM + ccS;
  const u16* gB = Bg + (size_t)rowS * DIM + ccS;
  const size_t gH = (size_t)128 * DIM;

  // fragment-read swizzle: k-chunk q=kk*4+quad; col_u16 = (q ^ (row&7))*8
  const int cswz = lane16 & 7;                   // row&7 == lane16&7 for all frags
  const int ck0 = (quad ^ cswz) * 8;
  const int ck1 = ((4 + quad) ^ cswz) * 8;
  const int arow = (wR * 64 + lane16) * 64;      // + mi*1024, + hA*HALF
  const int brow = (wC * 32 + lane16) * 64;      // + ni*1024, + hB*HALF

  // prologue: stage tiles 0 (slot0) and 1 (slot1); per-tile order AL,BL,BH,AH.
  // Before ph0(0) need AL0,BL0; 12 newer loads -> vmcnt(12).
  {
    u16* s0 = lds;
    u16* s1 = lds + SLOT;
    stage_half(gA,            s0 + 0 * HALF, tid);   // AL0
    stage_half(gB,            s0 + 2 * HALF, tid);   // BL0
    stage_half(gB + gH,       s0 + 3 * HALF, tid);   // BH0
    stage_half(gA + gH,       s0 + 1 * HALF, tid);   // AH0
    stage_half(gA + GBK,      s1 + 0 * HALF, tid);   // AL1
    stage_half(gB + GBK,      s1 + 2 * HALF, tid);   // BL1
    stage_half(gB + gH + GBK, s1 + 3 * HALF, tid);   // BH1
    stage_half(gA + gH + GBK, s1 + 1 * HALF, tid);   // AH1
  }
  asm volatile("s_waitcnt vmcnt(12)" ::: "memory");
  __builtin_amdgcn_s_barrier();

  short8 af[4][2], bl[2][2], bh[2][2];

#pragma unroll 1
  for (int t = 0; t < GNT; ++t) {
    u16* S = lds + (t & 1) * SLOT;       // current tile AND stage target (t+2)
    const bool pf = (t + 2 < GNT);
    const size_t tg = (size_t)(t + 2) * GBK;

    // ---- ph0: read A-lo(8) + B-lo(4); MFMA Alo x Blo; wait BH(t)
#pragma unroll
    for (int mi = 0; mi < 4; mi++) {
      const u16* aa = S + arow + mi * 1024;
      af[mi][0] = *(const short8*)(aa + ck0);
      af[mi][1] = *(const short8*)(aa + ck1);
    }
#pragma unroll
    for (int ni = 0; ni < 2; ni++) {
      const u16* bb = S + 2 * HALF + brow + ni * 1024;
      bl[ni][0] = *(const short8*)(bb + ck0);
      bl[ni][1] = *(const short8*)(bb + ck1);
    }
    __builtin_amdgcn_s_barrier();
    __builtin_amdgcn_s_setprio(1);
#pragma unroll
    for (int mi = 0; mi < 4; mi++)
#pragma unroll
      for (int ni = 0; ni < 2; ni++) {
        acc[mi][ni] = __builtin_amdgcn_mfma_f32_16x16x32_bf16(af[mi][0], bl[ni][0], acc[mi][ni], 0, 0, 0);
        acc[mi][ni] = __builtin_amdgcn_mfma_f32_16x16x32_bf16(af[mi][1], bl[ni][1], acc[mi][ni], 0, 0, 0);
      }
    __builtin_amdgcn_s_setprio(0);
    if (t + 1 < GNT) { asm volatile("s_waitcnt vmcnt(10)" ::: "memory"); }
    else             { asm volatile("s_waitcnt vmcnt(2)"  ::: "memory"); }
    __builtin_amdgcn_s_barrier();

    // ---- ph1: read B-hi(4); stage AL,BL(t+2); MFMA Alo x Bhi; wait AH(t)
#pragma unroll
    for (int ni = 0; ni < 2; ni++) {
      const u16* bb = S + 3 * HALF + brow + ni * 1024;
      bh[ni][0] = *(const short8*)(bb + ck0);
      bh[ni][1] = *(const short8*)(bb + ck1);
    }
    if (pf) {
      stage_half(gA + tg, S + 0 * HALF, tid);        // AL(t+2)
      stage_half(gB + tg, S + 2 * HALF, tid);        // BL(t+2)
    }
    __builtin_amdgcn_s_barrier();
    __builtin_amdgcn_s_setprio(1);
#pragma unroll
    for (int mi = 0; mi < 4; mi++)
#pragma unroll
      for (int ni = 0; ni < 2; ni++) {
        acc[mi][2 + ni] = __builtin_amdgcn_mfma_f32_16x16x32_bf16(af[mi][0], bh[ni][0], acc[mi][2 + ni], 0, 0, 0);
        acc[mi][2 + ni] = __builtin_amdgcn_mfma_f32_16x16x32_bf16(af[mi][1], bh[ni][1], acc[mi][2 + ni], 0, 0, 0);
      }
    __builtin_amdgcn_s_setprio(0);
    if (pf)                { asm volatile("s_waitcnt vmcnt(12)" ::: "memory"); }
    else if (t + 2 == GNT) { asm volatile("s_waitcnt vmcnt(8)"  ::: "memory"); }
    else                   { asm volatile("s_waitcnt vmcnt(0)"  ::: "memory"); }
    __builtin_amdgcn_s_barrier();

    // ---- ph2: read A-hi(8); stage BH(t+2); MFMA Ahi x Blo (bl from regs)
#pragma unroll
    for (int mi = 0; mi < 4; mi++) {
      const u16* aa = S + HALF + arow + mi * 1024;
      af[mi][0] = *(const short8*)(aa + ck0);
      af[mi][1] = *(const short8*)(aa + ck1);
    }
    if (pf) stage_half(gB + gH + tg, S + 3 * HALF, tid);   // BH(t+2)
    __builtin_amdgcn_s_barrier();
    __builtin_amdgcn_s_setprio(1);
#pragma unroll
    for (int mi = 0; mi < 4; mi++)
#pragma unroll
      for (int ni = 0; ni < 2; ni++) {
        acc[4 + mi][ni] = __builtin_amdgcn_mfma_f32_16x16x32_bf16(af[mi][0], bl[ni][0], acc[4 + mi][ni], 0, 0, 0);
        acc[4 + mi][ni] = __builtin_amdgcn_mfma_f32_16x16x32_bf16(af[mi][1], bl[ni][1], acc[4 + mi][ni], 0, 0, 0);
      }
    __builtin_amdgcn_s_setprio(0);
    __builtin_amdgcn_s_barrier();                          // no vmcnt

    // ---- ph3: stage AH(t+2); MFMA Ahi x Bhi (af, bh from regs); wait AL,BL(t+1)
    if (pf) stage_half(gA + gH + tg, S + 1 * HALF, tid);   // AH(t+2)
    __builtin_amdgcn_s_barrier();
    __builtin_amdgcn_s_setprio(1);
#pragma unroll
    for (int mi = 0; mi < 4; mi++)
#pragma unroll
      for (int ni = 0; ni < 2; ni++) {
        acc[4 + mi][2 + ni] = __builtin_amdgcn_mfma_f32_16x16x32_bf16(af[mi][0], bh[ni][0], acc[4 + mi][2 + ni], 0, 0, 0);
        acc[4 + mi][2 + ni] = __builtin_amdgcn_mfma_f32_16x16x32_bf16(af[mi][1], bh[ni][1], acc[4 + mi][2 + ni], 0, 0, 0);
      }
    __builtin_amdgcn_s_setprio(0);
    if (pf)                { asm volatile("s_waitcnt vmcnt(12)" ::: "memory"); }
    else if (t + 2 == GNT) { asm volatile("s_waitcnt vmcnt(4)"  ::: "memory"); }
    __builtin_amdgcn_s_barrier();
  }
}

// ---------- G1: gate GEMMs (i/f/g), 768 blocks, XCD 4m x 8n supertiles
__global__ __launch_bounds__(512, 2) void gemm_gates8(
    const u16* __restrict__ XB, const u16* __restrict__ WT,
    const float* __restrict__ s_i, const float* __restrict__ s_f, const float* __restrict__ s_g,
    const float* __restrict__ gnw, const float* __restrict__ s_o,
    u16* __restrict__ Ib, u16* __restrict__ Fb, u16* __restrict__ Gb) {
  __shared__ __align__(16) u16 lds[2 * SLOT];  // 128 KiB
  const int bid = blockIdx.x;
  const int i = (bid & 7) * 96 + (bid >> 3);    // XCD chunk of 96 logical blocks
  const int gate = i >> 8;                      // 0..2
  const int r = i & 255;
  const int sr = r >> 5;                        // 8 super-rows of 4 m-tiles
  const int s = r & 31;                         // 4m x 8n co-resident window
  const int m0 = (sr * 4 + (s & 3)) * GBM;
  const int n0 = (s >> 2) * GBN;

  const u16* Ag = XB + (size_t)m0 * DIM;
  const u16* Bg = WT + (size_t)gate * DIM * DIM + (size_t)n0 * DIM;

  f32x4 acc[8][4];
#pragma unroll
  for (int a = 0; a < 8; a++)
#pragma unroll
    for (int b = 0; b < 4; b++) acc[a][b] = {0.f, 0.f, 0.f, 0.f};

  kloop256(Ag, Bg, lds, acc);

  // epilogue: scale+activation, LDS transpose in two FULLY-UNROLLED 128-col
  // passes (p must be compile-time: acc indexed by p — rule #20).
  __syncthreads();
  const int tid = threadIdx.x;
  const int lane16 = tid & 15;
  const int quad = (tid & 63) >> 4;
  const int wid = tid >> 6;
  const int wR = wid >> 2;
  const int wC = wid & 3;
  const float* __restrict__ sc = (gate == 0) ? s_i : (gate == 1) ? s_f : s_g;
  u16* __restrict__ Out = (gate == 0) ? Ib : (gate == 1) ? Fb : Gb;
  u16* T = lds;  // [256][136] u16 (68 KB)
#pragma unroll
  for (int p = 0; p < 2; ++p) {
#pragma unroll
    for (int ni = 0; ni < 2; ++ni) {
      const int tcol = wC * 32 + ni * 16 + lane16;
      const int n = n0 + p * 128 + tcol;
      const float scale = sc[n];
      const float post = (gate == 2) ? gnw[n] * s_o[n] : 0.f;
#pragma unroll
      for (int hA = 0; hA < 2; ++hA)
#pragma unroll
        for (int mi = 0; mi < 4; ++mi) {
          const int lrow = hA * 128 + wR * 64 + mi * 16 + quad * 4;
#pragma unroll
          for (int r2 = 0; r2 < 4; ++r2) {
            float v = acc[hA * 4 + mi][p * 2 + ni][r2] * scale;
            if (gate == 1) v = 1.0f / (1.0f + expf(-v));        // sigmoid(f)
            if (gate == 2) v = v / (1.0f + expf(-v)) * post;    // swish(g)*gnw*s_o
            T[(lrow + r2) * 136 + tcol] = f2bf_rne(v);
          }
        }
    }
    __syncthreads();
#pragma unroll
    for (int j = 0; j < 8; j++) {
      const int id = tid + j * 512;          // 0..4095
      const int row = id >> 4;
      const int c16 = id & 15;
      uint4 v = *(const uint4*)(T + row * 136 + c16 * 8);
      *(uint4*)(Out + (size_t)(m0 + row) * DIM + n0 + p * 128 + c16 * 8) = v;
    }
    __syncthreads();
  }
}

// ---------- G2: out = to_fixed(OS @ WOB^T), 256 blocks, XCD 4m x 8n
__global__ __launch_bounds__(512, 2) void gemm_out8(const u16* __restrict__ OS,
                                                    const u16* __restrict__ WOB,
                                                    float* __restrict__ out) {
  __shared__ __align__(16) u16 lds[2 * SLOT];  // 128 KiB
  const int bid = blockIdx.x;
  const int l = bid >> 3;
  const int m0 = ((bid & 7) * 4 + (l & 3)) * GBM;
  const int n0 = (l >> 2) * GBN;

  const u16* Ag = OS + (size_t)m0 * DIM;
  const u16* Bg = WOB + (size_t)n0 * DIM;

  f32x4 acc[8][4];
#pragma unroll
  for (int a = 0; a < 8; a++)
#pragma unroll
    for (int b = 0; b < 4; b++) acc[a][b] = {0.f, 0.f, 0.f, 0.f};

  kloop256(Ag, Bg, lds, acc);

  // epilogue: direct f32 stores, all indices static
  const int tid = threadIdx.x;
  const int lane16 = tid & 15;
  const int quad = (tid & 63) >> 4;
  const int wid = tid >> 6;
  const int wR = wid >> 2;
  const int wC = wid & 3;
#pragma unroll
  for (int p = 0; p < 2; ++p)
#pragma unroll
    for (int ni = 0; ni < 2; ++ni) {
      const int n = n0 + p * 128 + wC * 32 + ni * 16 + lane16;
#pragma unroll
      for (int hA = 0; hA < 2; ++hA)
#pragma unroll
        for (int mi = 0; mi < 4; ++mi) {
          const int mrow = m0 + hA * 128 + wR * 64 + mi * 16 + quad * 4;
#pragma unroll
          for (int r2 = 0; r2 < 4; ++r2)
            out[(size_t)(mrow + r2) * DIM + n] =
                rintf(acc[hA * 4 + mi][p * 2 + ni][r2] * 256.0f) * 0.00390625f;
        }
    }
}

// ---------- S1: per-chunk local scan carries; 2 adjacent e per thread
__global__ __launch_bounds__(256) void scan_phase1(const u16* __restrict__ Fb,
                                                   const u16* __restrict__ Ib,
                                                   float* __restrict__ Pc,
                                                   float* __restrict__ Sc) {
  const int e0 = (blockIdx.x * 256 + threadIdx.x) * 2;
  const int c = blockIdx.y;
  const int b = blockIdx.z;
  const size_t base = ((size_t)b * SEQ + (size_t)c * TCH) * DIM + e0;
  float P0 = 1.f, S0 = 0.f, P1 = 1.f, S1 = 0.f;
  for (int t = 0; t < TCH; t++) {
    const uint32_t fp = *(const uint32_t*)(Fb + base + (size_t)t * DIM);
    const uint32_t ip = *(const uint32_t*)(Ib + base + (size_t)t * DIM);
    const float f0 = bf2f((u16)fp), f1 = bf2f((u16)(fp >> 16));
    const float i0 = bf2f((u16)ip), i1 = bf2f((u16)(ip >> 16));
    S0 = S0 * f0 + (1.f - f0) * i0;  P0 *= f0;
    S1 = S1 * f1 + (1.f - f1) * i1;  P1 *= f1;
  }
  const size_t ci = ((size_t)b * NCH + c) * DIM + e0;
  *(float2*)(Pc + ci) = make_float2(P0, P1);
  *(float2*)(Sc + ci) = make_float2(S0, S1);
}

// ---------- S2: combine carries, recompute in-chunk h, write Hb (bf16)
__global__ __launch_bounds__(256) void scan_phase2(const u16* __restrict__ Fb,
                                                   const u16* __restrict__ Ib,
                                                   const float* __restrict__ Pc,
                                                   const float* __restrict__ Sc,
                                                   u16* __restrict__ Hb) {
  const int e0 = (blockIdx.x * 256 + threadIdx.x) * 2;
  const int c = blockIdx.y;
  const int b = blockIdx.z;
  float h0 = 0.f, h1 = 0.f;
  for (int cc = 0; cc < c; cc++) {
    const size_t ci = ((size_t)b * NCH + cc) * DIM + e0;
    const float2 p = *(const float2*)(Pc + ci);
    const float2 s = *(const float2*)(Sc + ci);
    h0 = s.x + p.x * h0;
    h1 = s.y + p.y * h1;
  }
  const size_t base = ((size_t)b * SEQ + (size_t)c * TCH) * DIM + e0;
  for (int t = 0; t < TCH; t++) {
    const uint32_t fp = *(const uint32_t*)(Fb + base + (size_t)t * DIM);
    const uint32_t ip = *(const uint32_t*)(Ib + base + (size_t)t * DIM);
    const float f0 = bf2f((u16)fp), f1 = bf2f((u16)(fp >> 16));
    const float i0 = bf2f((u16)ip), i1 = bf2f((u16)(ip >> 16));
    h0 = f0 * h0 + (1.f - f0) * i0;
    h1 = f1 * h1 + (1.f - f1) * i1;
    *(uint32_t*)(Hb + base + (size_t)t * DIM) =
        (uint32_t)f2bf_rne(h0) | ((uint32_t)f2bf_rne(h1) << 16);
  }
}

// ---------- K4: per-row RMS, multiply pre-fused gate, write OS (bf16)
__global__ __launch_bounds__(256) void rms_gate(const u16* __restrict__ Hb,
                                                const u16* __restrict__ SwGb,
                                                u16* __restrict__ OS) {
  const size_t base = (size_t)blockIdx.x * DIM;
  const int tid = threadIdx.x;
  const int e0 = tid * 8;
  uint4 hp = *(const uint4*)(Hb + base + e0);
  float hv[8];
  hv[0] = bf2f((u16)hp.x); hv[1] = bf2f((u16)(hp.x >> 16));
  hv[2] = bf2f((u16)hp.y); hv[3] = bf2f((u16)(hp.y >> 16));
  hv[4] = bf2f((u16)hp.z); hv[5] = bf2f((u16)(hp.z >> 16));
  hv[6] = bf2f((u16)hp.w); hv[7] = bf2f((u16)(hp.w >> 16));
  float ss = 0.f;
#pragma unroll
  for (int j = 0; j < 8; j++) ss += hv[j] * hv[j];
#pragma unroll
  for (int off = 32; off > 0; off >>= 1) ss += __shfl_down(ss, off, 64);
  __shared__ float red[4];
  if ((tid & 63) == 0) red[tid >> 6] = ss;
  __syncthreads();
  const float tot = red[0] + red[1] + red[2] + red[3];
  const float inv = 1.0f / sqrtf(tot * (1.0f / (float)DIM) + 1e-5f);

  uint4 gp = *(const uint4*)(SwGb + base + e0);
  float gv[8];
  gv[0] = bf2f((u16)gp.x); gv[1] = bf2f((u16)(gp.x >> 16));
  gv[2] = bf2f((u16)gp.y); gv[3] = bf2f((u16)(gp.y >> 16));
  gv[4] = bf2f((u16)gp.z); gv[5] = bf2f((u16)(gp.z >> 16));
  gv[6] = bf2f((u16)gp.w); gv[7] = bf2f((u16)(gp.w >> 16));
  u16 ov[8];
#pragma unroll
  for (int j = 0; j < 8; j++) ov[j] = f2bf_rne(hv[j] * inv * gv[j]);
  uint4 op;
  op.x = (uint32_t)ov[0] | ((uint32_t)ov[1] << 16);
  op.y = (uint32_t)ov[2] | ((uint32_t)ov[3] << 16);
  op.z = (uint32_t)ov[4] | ((uint32_t)ov[5] << 16);
  op.w = (uint32_t)ov[6] | ((uint32_t)ov[7] << 16);
  *(uint4*)(OS + base + e0) = op;
}

extern "C" void kernel_launch(void* const* d_in, const int* in_sizes, int n_in,
                              void* d_out, int out_size, void* d_ws, size_t ws_size,
                              hipStream_t stream) {
  (void)in_sizes; (void)n_in; (void)out_size;
  const float* x   = (const float*)d_in[0];
  const float* w_i = (const float*)d_in[1];
  const float* w_f = (const float*)d_in[2];
  const float* w_g = (const float*)d_in[3];
  const float* w_o = (const float*)d_in[4];
  const float* s_i = (const float*)d_in[5];
  const float* s_f = (const float*)d_in[6];
  const float* s_g = (const float*)d_in[7];
  const float* s_o = (const float*)d_in[8];
  const float* gnw = (const float*)d_in[9];
  float* out = (float*)d_out;

  const size_t MB = 1024 * 1024;
  const size_t NEED = 88 * MB;
  if (ws_size < NEED) {
    diag_ws<<<MROWS * DIM / 2048, 256, 0, stream>>>(out, (float)(ws_size / MB));
    return;
  }

  uint8_t* ws = (uint8_t*)d_ws;
  u16* XB = (u16*)(ws);                    // [0, 32M)
  u16* WT = (u16*)(ws + 32 * MB);          // [32M, 56M), dead after gemm_gates
  u16* Ib = (u16*)(ws + 56 * MB);          // [56M, 88M)
  float* Pc = (float*)(ws + 32 * MB);      // overlay dead WT: 1 MB
  float* Sc = (float*)(ws + 33 * MB);      // 1 MB
  u16* WOB = (u16*)(ws + 34 * MB);         // 8 MB, written after scan
  u16* Hb  = XB;                           // alias: XB dead after gemm_gates
  u16* OS  = Ib;                           // alias: Ib dead after scan_phase2
  u16* Gb = (u16*)d_out;                   // d_out scratch [0,32M): swish-gate
  u16* Fb = (u16*)((uint8_t*)d_out + 32 * MB);  // [32M,64M): sigmoid f

  prep_x<<<MROWS * DIM / 1024, 256, 0, stream>>>(x, XB);
  prep_wT<<<dim3(DIM / 32, DIM / 32, 3), dim3(32, 8, 1), 0, stream>>>(w_i, w_f, w_g, WT);
  gemm_gates8<<<768, 512, 0, stream>>>(XB, WT, s_i, s_f, s_g, gnw, s_o, Ib, Fb, Gb);
  scan_phase1<<<dim3(DIM / 512, NCH, BATCH), 256, 0, stream>>>(Fb, Ib, Pc, Sc);
  scan_phase2<<<dim3(DIM / 512, NCH, BATCH), 256, 0, stream>>>(Fb, Ib, Pc, Sc, Hb);
  prep_wo<<<DIM * DIM / 1024, 256, 0, stream>>>(w_o, WOB);
  rms_gate<<<MROWS, 256, 0, stream>>>(Hb, Gb, OS);
  gemm_out8<<<256, 512, 0, stream>>>(OS, WOB, out);
}

// Round 7
// 492.753 us; speedup vs baseline: 1.0625x; 1.0625x over previous
//
#include <hip/hip_runtime.h>
#include <hip/hip_bf16.h>
#include <stdint.h>
#include <math.h>

// FixedPointHGRNAttention on MI355X — r10: register-level software pipelining.
// r7/r8/r9 post-mortem: all pinned at MfmaUtil ~35% because every phase was
// {ds_read -> barrier -> MFMA} — LDS pipe and matrix pipe strictly serial
// (6025 cyc/tile observed = 2048 MFMA + ~2800 LDS + sync, in SERIES).
// r10 issues each MFMA group's fragment reads ONE GROUP AHEAD:
//   G0: issue bh(t) reads   ; MFMA a0 x bl   (a0,bl read in G3 of t-1)
//   G1: issue a1(t) reads   ; MFMA a0 x bh
//   G2:                      MFMA a1 x bl
//   __syncthreads()  — vmcnt(0) retires stage(t+1) issued a FULL TILE ago
//                      (stale drain, ~free); fences cooperative staging.
//   G3: stage(t+2)->slot(t) ; read a0,bl(t+1) from slot(t+1); MFMA a1 x bh
// One barrier/tile; every read covered by >=1 MFMA group of compute.
// LDS WAR safety: all slot-t reads are register-resident before the boundary
// barrier (per-wave lgkm waits precede G2's MFMA), so stage(t+2) into slot(t)
// after the barrier races nothing.
// 256x256 tile, BK=64, 8 waves, 128 KiB LDS (2 slots x {AL,AH,BL,BH}).
// Spill-safe flat acc[8][4], all indices compile-time (rule #20).
// XOR-swizzled LDS via pre-swizzled global_load_lds source.
// XCD 4m x 8n co-resident supertiles (FETCH 406->148 MB since r7).
//
// ws layout (88 MiB needed):
//   [0,   32M)  XB  bf16 [8192][2048]       -> later Hb (aliased)
//   [32M, 56M)  WT  bf16 [3][2048][2048]    (dead after gemm_gates)
//       [32M,33M) Pc, [33M,34M) Sc  (scan carries, overlay dead WT)
//       [34M,42M) WOB bf16 [2048][2048]     (w_o, written after scan)
//   [56M, 88M)  Ib  bf16 [8192][2048]       -> later OS (aliased)
// d_out scratch (64 MiB, overwritten by gemm_out):
//   Gb = d_out[0,32M)  (swish(g)*gnw*s_o), Fb = d_out[32M,64M) (sigmoid f)

#define BATCH 4
#define SEQ   2048
#define DIM   2048
#define MROWS (BATCH*SEQ)   // 8192
#define TCH   64
#define NCH   (SEQ/TCH)     // 32

// GEMM geometry: 256x256 tile, BK=64, 8 waves (2 row-bands x 4 col-bands)
#define GBM 256
#define GBN 256
#define GBK 64
#define GNT (DIM/GBK)        // 32 K-tiles
#define HALF 8192            // u16 per half-tile (128 rows x 64 cols)
#define SLOT (4*HALF)        // u16 per dbuf slot: {AL, AH, BL, BH}

typedef unsigned short u16;
typedef __attribute__((ext_vector_type(8))) short short8;
typedef __attribute__((ext_vector_type(4))) float f32x4;

static __device__ __forceinline__ u16 f2bf_rne(float x) {
  uint32_t u = __float_as_uint(x);
  u += 0x7FFFu + ((u >> 16) & 1u);
  return (u16)(u >> 16);
}
static __device__ __forceinline__ float bf2f(u16 h) {
  return __uint_as_float(((uint32_t)h) << 16);
}

static __device__ __forceinline__ void gl2lds16(const void* g, void* l) {
  __builtin_amdgcn_global_load_lds((const __attribute__((address_space(1))) void*)g,
                                   (__attribute__((address_space(3))) void*)l,
                                   16, 0, 0);
}

// ---------- diagnostic path (ws too small): absmax ~= ws_size MiB
__global__ __launch_bounds__(256) void diag_ws(float* __restrict__ out, float val) {
  size_t i = ((size_t)blockIdx.x * 256 + threadIdx.x) * 8;
#pragma unroll
  for (int j = 0; j < 8; j++) out[i + j] = val;
}

// ---------- P1: x -> to_fixed -> bf16 (RNE)
__global__ __launch_bounds__(256) void prep_x(const float* __restrict__ x,
                                              u16* __restrict__ XB) {
  size_t i = ((size_t)blockIdx.x * 256 + threadIdx.x) * 4;
  float4 v = *(const float4*)(x + i);
  float q[4] = {v.x, v.y, v.z, v.w};
  u16 hh[4];
#pragma unroll
  for (int j = 0; j < 4; j++) {
    float xq = rintf(q[j] * 256.0f) * 0.00390625f;
    hh[j] = f2bf_rne(xq);
  }
  *(uint2*)(XB + i) = make_uint2((uint32_t)hh[0] | ((uint32_t)hh[1] << 16),
                                 (uint32_t)hh[2] | ((uint32_t)hh[3] << 16));
}

// ---------- P2a: transpose w_i/w_f/w_g (DxE ternary) -> WT[g][e][d] bf16
__global__ void prep_wT(const float* __restrict__ w_i, const float* __restrict__ w_f,
                        const float* __restrict__ w_g, u16* __restrict__ WT) {
  __shared__ u16 tile[32][33];
  const int g = blockIdx.z;
  const float* __restrict__ w = (g == 0) ? w_i : (g == 1) ? w_f : w_g;
  u16* __restrict__ outp = WT + (size_t)g * DIM * DIM;
  const int d0 = blockIdx.x * 32;
  const int e0 = blockIdx.y * 32;
  const int tx = threadIdx.x;
  const int ty = threadIdx.y;
  for (int ii = ty; ii < 32; ii += 8)
    tile[ii][tx] = f2bf_rne(w[(size_t)(d0 + ii) * DIM + e0 + tx]);
  __syncthreads();
  for (int ii = ty; ii < 32; ii += 8)
    outp[(size_t)(e0 + ii) * DIM + d0 + tx] = tile[tx][ii];
}

// ---------- P2b: w_o [O][E] -> bf16 (already B^T layout)
__global__ __launch_bounds__(256) void prep_wo(const float* __restrict__ w, u16* __restrict__ WB) {
  size_t i = ((size_t)blockIdx.x * 256 + threadIdx.x) * 4;
  float4 v = *(const float4*)(w + i);
  *(uint2*)(WB + i) = make_uint2((uint32_t)f2bf_rne(v.x) | ((uint32_t)f2bf_rne(v.y) << 16),
                                 (uint32_t)f2bf_rne(v.z) | ((uint32_t)f2bf_rne(v.w) << 16));
}

// ---------- staging: one 128x64 half-tile, 2 gl2lds16/thread, linear LDS dest,
// global source pre-swizzled: LDS chunk c holds global (row=c>>3, (c&7)^(row&7)).
static __device__ __forceinline__ void stage_half(const u16* g, u16* l, int tid) {
  gl2lds16(g, l + (size_t)tid * 8);
  gl2lds16(g + (size_t)64 * DIM, l + (size_t)(tid + 512) * 8);
}

// ---------- K-loop: register-pipelined, one barrier/tile (see header comment).
static __device__ __forceinline__ void kloop256(const u16* __restrict__ Ag,
                                                const u16* __restrict__ Bg,
                                                u16* lds, f32x4 (&acc)[8][4]) {
  const int tid = threadIdx.x;
  const int lane16 = tid & 15;
  const int quad = (tid & 63) >> 4;
  const int wid = tid >> 6;
  const int wR = wid >> 2;      // 0..1: 64-row band within each 128-row half
  const int wC = wid & 3;       // 0..3: 32-col band within each 128-col half

  // staging source: chunk c = tid + j*512 -> row=c>>3, col-chunk=(c&7)^(row&7)
  const int rowS = tid >> 3;                     // 0..63 (j adds 64; row&7 invariant)
  const int ccS = ((tid & 7) ^ (rowS & 7)) * 8;
  const u16* gA = Ag + (size_t)rowS * DIM + ccS;
  const u16* gB = Bg + (size_t)rowS * DIM + ccS;
  const size_t gH = (size_t)128 * DIM;

  // fragment-read swizzle: k-chunk q=kk*4+quad; col_u16 = (q ^ (row&7))*8
  const int cswz = lane16 & 7;                   // row&7 == lane16&7 for all frags
  const int ck0 = (quad ^ cswz) * 8;
  const int ck1 = ((4 + quad) ^ cswz) * 8;
  const int arow = (wR * 64 + lane16) * 64;      // + mi*1024, + hA*HALF
  const int brow = (wC * 32 + lane16) * 64;      // + ni*1024, + hB*HALF

  // prologue: stage tiles 0 (slot0) and 1 (slot1); full drain (once per block,
  // ~700 cyc — negligible over 32 tiles) gives both slots resident.
  {
    u16* s0 = lds;
    u16* s1 = lds + SLOT;
    stage_half(gA,            s0 + 0 * HALF, tid);   // AL0
    stage_half(gB,            s0 + 2 * HALF, tid);   // BL0
    stage_half(gB + gH,       s0 + 3 * HALF, tid);   // BH0
    stage_half(gA + gH,       s0 + 1 * HALF, tid);   // AH0
    stage_half(gA + GBK,      s1 + 0 * HALF, tid);   // AL1
    stage_half(gB + GBK,      s1 + 2 * HALF, tid);   // BL1
    stage_half(gB + gH + GBK, s1 + 3 * HALF, tid);   // BH1
    stage_half(gA + gH + GBK, s1 + 1 * HALF, tid);   // AH1
  }
  __syncthreads();

  short8 a0[4][2], a1[4][2], bl[2][2], bh[2][2];

  // preload a0(0), bl(0) from slot0
  {
    const u16* S = lds;
#pragma unroll
    for (int mi = 0; mi < 4; mi++) {
      const u16* aa = S + arow + mi * 1024;
      a0[mi][0] = *(const short8*)(aa + ck0);
      a0[mi][1] = *(const short8*)(aa + ck1);
    }
#pragma unroll
    for (int ni = 0; ni < 2; ni++) {
      const u16* bb = S + 2 * HALF + brow + ni * 1024;
      bl[ni][0] = *(const short8*)(bb + ck0);
      bl[ni][1] = *(const short8*)(bb + ck1);
    }
  }

#pragma unroll 1
  for (int t = 0; t < GNT; ++t) {
    u16* S = lds + (t & 1) * SLOT;        // current tile; stage target for t+2
    u16* SN = lds + ((t + 1) & 1) * SLOT; // next tile (resident)

    // ---- G0: issue bh(t) reads; MFMA a0 x bl -> acc[0..3][0..1]
#pragma unroll
    for (int ni = 0; ni < 2; ni++) {
      const u16* bb = S + 3 * HALF + brow + ni * 1024;
      bh[ni][0] = *(const short8*)(bb + ck0);
      bh[ni][1] = *(const short8*)(bb + ck1);
    }
    __builtin_amdgcn_s_setprio(1);
#pragma unroll
    for (int mi = 0; mi < 4; mi++)
#pragma unroll
      for (int ni = 0; ni < 2; ni++) {
        acc[mi][ni] = __builtin_amdgcn_mfma_f32_16x16x32_bf16(a0[mi][0], bl[ni][0], acc[mi][ni], 0, 0, 0);
        acc[mi][ni] = __builtin_amdgcn_mfma_f32_16x16x32_bf16(a0[mi][1], bl[ni][1], acc[mi][ni], 0, 0, 0);
      }
    __builtin_amdgcn_s_setprio(0);

    // ---- G1: issue a1(t) reads; MFMA a0 x bh -> acc[0..3][2..3]
#pragma unroll
    for (int mi = 0; mi < 4; mi++) {
      const u16* aa = S + HALF + arow + mi * 1024;
      a1[mi][0] = *(const short8*)(aa + ck0);
      a1[mi][1] = *(const short8*)(aa + ck1);
    }
    __builtin_amdgcn_s_setprio(1);
#pragma unroll
    for (int mi = 0; mi < 4; mi++)
#pragma unroll
      for (int ni = 0; ni < 2; ni++) {
        acc[mi][2 + ni] = __builtin_amdgcn_mfma_f32_16x16x32_bf16(a0[mi][0], bh[ni][0], acc[mi][2 + ni], 0, 0, 0);
        acc[mi][2 + ni] = __builtin_amdgcn_mfma_f32_16x16x32_bf16(a0[mi][1], bh[ni][1], acc[mi][2 + ni], 0, 0, 0);
      }
    __builtin_amdgcn_s_setprio(0);

    // ---- G2: MFMA a1 x bl -> acc[4..7][0..1] (a1 lgkm-waited here)
    __builtin_amdgcn_s_setprio(1);
#pragma unroll
    for (int mi = 0; mi < 4; mi++)
#pragma unroll
      for (int ni = 0; ni < 2; ni++) {
        acc[4 + mi][ni] = __builtin_amdgcn_mfma_f32_16x16x32_bf16(a1[mi][0], bl[ni][0], acc[4 + mi][ni], 0, 0, 0);
        acc[4 + mi][ni] = __builtin_amdgcn_mfma_f32_16x16x32_bf16(a1[mi][1], bl[ni][1], acc[4 + mi][ni], 0, 0, 0);
      }
    __builtin_amdgcn_s_setprio(0);

    // ---- boundary: vmcnt(0)+lgkmcnt(0)+barrier (compiler-fenced).
    // Only outstanding vmem = stage(t+1), issued a full tile ago -> stale
    // drain, ~free. Makes slot(t+1) (cooperatively staged) visible to all.
    __syncthreads();

    // ---- G3: read a0,bl(t+1) from SN; stage(t+2) -> S; MFMA a1 x bh
    if (t + 1 < GNT) {
#pragma unroll
      for (int mi = 0; mi < 4; mi++) {
        const u16* aa = SN + arow + mi * 1024;
        a0[mi][0] = *(const short8*)(aa + ck0);
        a0[mi][1] = *(const short8*)(aa + ck1);
      }
#pragma unroll
      for (int ni = 0; ni < 2; ni++) {
        const u16* bb = SN + 2 * HALF + brow + ni * 1024;
        bl[ni][0] = *(const short8*)(bb + ck0);
        bl[ni][1] = *(const short8*)(bb + ck1);
      }
    }
    if (t + 2 < GNT) {
      const size_t tg = (size_t)(t + 2) * GBK;
      stage_half(gA + tg,      S + 0 * HALF, tid);   // AL(t+2)
      stage_half(gB + tg,      S + 2 * HALF, tid);   // BL(t+2)
      stage_half(gB + gH + tg, S + 3 * HALF, tid);   // BH(t+2)
      stage_half(gA + gH + tg, S + 1 * HALF, tid);   // AH(t+2)
    }
    __builtin_amdgcn_s_setprio(1);
#pragma unroll
    for (int mi = 0; mi < 4; mi++)
#pragma unroll
      for (int ni = 0; ni < 2; ni++) {
        acc[4 + mi][2 + ni] = __builtin_amdgcn_mfma_f32_16x16x32_bf16(a1[mi][0], bh[ni][0], acc[4 + mi][2 + ni], 0, 0, 0);
        acc[4 + mi][2 + ni] = __builtin_amdgcn_mfma_f32_16x16x32_bf16(a1[mi][1], bh[ni][1], acc[4 + mi][2 + ni], 0, 0, 0);
      }
    __builtin_amdgcn_s_setprio(0);
  }
}

// ---------- G1: gate GEMMs (i/f/g), 768 blocks, XCD 4m x 8n supertiles
__global__ __launch_bounds__(512, 2) void gemm_gates8(
    const u16* __restrict__ XB, const u16* __restrict__ WT,
    const float* __restrict__ s_i, const float* __restrict__ s_f, const float* __restrict__ s_g,
    const float* __restrict__ gnw, const float* __restrict__ s_o,
    u16* __restrict__ Ib, u16* __restrict__ Fb, u16* __restrict__ Gb) {
  __shared__ __align__(16) u16 lds[2 * SLOT];  // 128 KiB
  const int bid = blockIdx.x;
  const int i = (bid & 7) * 96 + (bid >> 3);    // XCD chunk of 96 logical blocks
  const int gate = i >> 8;                      // 0..2
  const int r = i & 255;
  const int sr = r >> 5;                        // 8 super-rows of 4 m-tiles
  const int s = r & 31;                         // 4m x 8n co-resident window
  const int m0 = (sr * 4 + (s & 3)) * GBM;
  const int n0 = (s >> 2) * GBN;

  const u16* Ag = XB + (size_t)m0 * DIM;
  const u16* Bg = WT + (size_t)gate * DIM * DIM + (size_t)n0 * DIM;

  f32x4 acc[8][4];
#pragma unroll
  for (int a = 0; a < 8; a++)
#pragma unroll
    for (int b = 0; b < 4; b++) acc[a][b] = {0.f, 0.f, 0.f, 0.f};

  kloop256(Ag, Bg, lds, acc);

  // epilogue: scale+activation, LDS transpose in two FULLY-UNROLLED 128-col
  // passes (p must be compile-time: acc indexed by p — rule #20).
  __syncthreads();
  const int tid = threadIdx.x;
  const int lane16 = tid & 15;
  const int quad = (tid & 63) >> 4;
  const int wid = tid >> 6;
  const int wR = wid >> 2;
  const int wC = wid & 3;
  const float* __restrict__ sc = (gate == 0) ? s_i : (gate == 1) ? s_f : s_g;
  u16* __restrict__ Out = (gate == 0) ? Ib : (gate == 1) ? Fb : Gb;
  u16* T = lds;  // [256][136] u16 (68 KB)
#pragma unroll
  for (int p = 0; p < 2; ++p) {
#pragma unroll
    for (int ni = 0; ni < 2; ++ni) {
      const int tcol = wC * 32 + ni * 16 + lane16;
      const int n = n0 + p * 128 + tcol;
      const float scale = sc[n];
      const float post = (gate == 2) ? gnw[n] * s_o[n] : 0.f;
#pragma unroll
      for (int hA = 0; hA < 2; ++hA)
#pragma unroll
        for (int mi = 0; mi < 4; ++mi) {
          const int lrow = hA * 128 + wR * 64 + mi * 16 + quad * 4;
#pragma unroll
          for (int r2 = 0; r2 < 4; ++r2) {
            float v = acc[hA * 4 + mi][p * 2 + ni][r2] * scale;
            if (gate == 1) v = 1.0f / (1.0f + expf(-v));        // sigmoid(f)
            if (gate == 2) v = v / (1.0f + expf(-v)) * post;    // swish(g)*gnw*s_o
            T[(lrow + r2) * 136 + tcol] = f2bf_rne(v);
          }
        }
    }
    __syncthreads();
#pragma unroll
    for (int j = 0; j < 8; j++) {
      const int id = tid + j * 512;          // 0..4095
      const int row = id >> 4;
      const int c16 = id & 15;
      uint4 v = *(const uint4*)(T + row * 136 + c16 * 8);
      *(uint4*)(Out + (size_t)(m0 + row) * DIM + n0 + p * 128 + c16 * 8) = v;
    }
    __syncthreads();
  }
}

// ---------- G2: out = to_fixed(OS @ WOB^T), 256 blocks, XCD 4m x 8n
__global__ __launch_bounds__(512, 2) void gemm_out8(const u16* __restrict__ OS,
                                                    const u16* __restrict__ WOB,
                                                    float* __restrict__ out) {
  __shared__ __align__(16) u16 lds[2 * SLOT];  // 128 KiB
  const int bid = blockIdx.x;
  const int l = bid >> 3;
  const int m0 = ((bid & 7) * 4 + (l & 3)) * GBM;
  const int n0 = (l >> 2) * GBN;

  const u16* Ag = OS + (size_t)m0 * DIM;
  const u16* Bg = WOB + (size_t)n0 * DIM;

  f32x4 acc[8][4];
#pragma unroll
  for (int a = 0; a < 8; a++)
#pragma unroll
    for (int b = 0; b < 4; b++) acc[a][b] = {0.f, 0.f, 0.f, 0.f};

  kloop256(Ag, Bg, lds, acc);

  // epilogue: direct f32 stores, all indices static
  const int tid = threadIdx.x;
  const int lane16 = tid & 15;
  const int quad = (tid & 63) >> 4;
  const int wid = tid >> 6;
  const int wR = wid >> 2;
  const int wC = wid & 3;
#pragma unroll
  for (int p = 0; p < 2; ++p)
#pragma unroll
    for (int ni = 0; ni < 2; ++ni) {
      const int n = n0 + p * 128 + wC * 32 + ni * 16 + lane16;
#pragma unroll
      for (int hA = 0; hA < 2; ++hA)
#pragma unroll
        for (int mi = 0; mi < 4; ++mi) {
          const int mrow = m0 + hA * 128 + wR * 64 + mi * 16 + quad * 4;
#pragma unroll
          for (int r2 = 0; r2 < 4; ++r2)
            out[(size_t)(mrow + r2) * DIM + n] =
                rintf(acc[hA * 4 + mi][p * 2 + ni][r2] * 256.0f) * 0.00390625f;
        }
    }
}

// ---------- S1: per-chunk local scan carries; 2 adjacent e per thread
__global__ __launch_bounds__(256) void scan_phase1(const u16* __restrict__ Fb,
                                                   const u16* __restrict__ Ib,
                                                   float* __restrict__ Pc,
                                                   float* __restrict__ Sc) {
  const int e0 = (blockIdx.x * 256 + threadIdx.x) * 2;
  const int c = blockIdx.y;
  const int b = blockIdx.z;
  const size_t base = ((size_t)b * SEQ + (size_t)c * TCH) * DIM + e0;
  float P0 = 1.f, S0 = 0.f, P1 = 1.f, S1 = 0.f;
  for (int t = 0; t < TCH; t++) {
    const uint32_t fp = *(const uint32_t*)(Fb + base + (size_t)t * DIM);
    const uint32_t ip = *(const uint32_t*)(Ib + base + (size_t)t * DIM);
    const float f0 = bf2f((u16)fp), f1 = bf2f((u16)(fp >> 16));
    const float i0 = bf2f((u16)ip), i1 = bf2f((u16)(ip >> 16));
    S0 = S0 * f0 + (1.f - f0) * i0;  P0 *= f0;
    S1 = S1 * f1 + (1.f - f1) * i1;  P1 *= f1;
  }
  const size_t ci = ((size_t)b * NCH + c) * DIM + e0;
  *(float2*)(Pc + ci) = make_float2(P0, P1);
  *(float2*)(Sc + ci) = make_float2(S0, S1);
}

// ---------- S2: combine carries, recompute in-chunk h, write Hb (bf16)
__global__ __launch_bounds__(256) void scan_phase2(const u16* __restrict__ Fb,
                                                   const u16* __restrict__ Ib,
                                                   const float* __restrict__ Pc,
                                                   const float* __restrict__ Sc,
                                                   u16* __restrict__ Hb) {
  const int e0 = (blockIdx.x * 256 + threadIdx.x) * 2;
  const int c = blockIdx.y;
  const int b = blockIdx.z;
  float h0 = 0.f, h1 = 0.f;
  for (int cc = 0; cc < c; cc++) {
    const size_t ci = ((size_t)b * NCH + cc) * DIM + e0;
    const float2 p = *(const float2*)(Pc + ci);
    const float2 s = *(const float2*)(Sc + ci);
    h0 = s.x + p.x * h0;
    h1 = s.y + p.y * h1;
  }
  const size_t base = ((size_t)b * SEQ + (size_t)c * TCH) * DIM + e0;
  for (int t = 0; t < TCH; t++) {
    const uint32_t fp = *(const uint32_t*)(Fb + base + (size_t)t * DIM);
    const uint32_t ip = *(const uint32_t*)(Ib + base + (size_t)t * DIM);
    const float f0 = bf2f((u16)fp), f1 = bf2f((u16)(fp >> 16));
    const float i0 = bf2f((u16)ip), i1 = bf2f((u16)(ip >> 16));
    h0 = f0 * h0 + (1.f - f0) * i0;
    h1 = f1 * h1 + (1.f - f1) * i1;
    *(uint32_t*)(Hb + base + (size_t)t * DIM) =
        (uint32_t)f2bf_rne(h0) | ((uint32_t)f2bf_rne(h1) << 16);
  }
}

// ---------- K4: per-row RMS, multiply pre-fused gate, write OS (bf16)
__global__ __launch_bounds__(256) void rms_gate(const u16* __restrict__ Hb,
                                                const u16* __restrict__ SwGb,
                                                u16* __restrict__ OS) {
  const size_t base = (size_t)blockIdx.x * DIM;
  const int tid = threadIdx.x;
  const int e0 = tid * 8;
  uint4 hp = *(const uint4*)(Hb + base + e0);
  float hv[8];
  hv[0] = bf2f((u16)hp.x); hv[1] = bf2f((u16)(hp.x >> 16));
  hv[2] = bf2f((u16)hp.y); hv[3] = bf2f((u16)(hp.y >> 16));
  hv[4] = bf2f((u16)hp.z); hv[5] = bf2f((u16)(hp.z >> 16));
  hv[6] = bf2f((u16)hp.w); hv[7] = bf2f((u16)(hp.w >> 16));
  float ss = 0.f;
#pragma unroll
  for (int j = 0; j < 8; j++) ss += hv[j] * hv[j];
#pragma unroll
  for (int off = 32; off > 0; off >>= 1) ss += __shfl_down(ss, off, 64);
  __shared__ float red[4];
  if ((tid & 63) == 0) red[tid >> 6] = ss;
  __syncthreads();
  const float tot = red[0] + red[1] + red[2] + red[3];
  const float inv = 1.0f / sqrtf(tot * (1.0f / (float)DIM) + 1e-5f);

  uint4 gp = *(const uint4*)(SwGb + base + e0);
  float gv[8];
  gv[0] = bf2f((u16)gp.x); gv[1] = bf2f((u16)(gp.x >> 16));
  gv[2] = bf2f((u16)gp.y); gv[3] = bf2f((u16)(gp.y >> 16));
  gv[4] = bf2f((u16)gp.z); gv[5] = bf2f((u16)(gp.z >> 16));
  gv[6] = bf2f((u16)gp.w); gv[7] = bf2f((u16)(gp.w >> 16));
  u16 ov[8];
#pragma unroll
  for (int j = 0; j < 8; j++) ov[j] = f2bf_rne(hv[j] * inv * gv[j]);
  uint4 op;
  op.x = (uint32_t)ov[0] | ((uint32_t)ov[1] << 16);
  op.y = (uint32_t)ov[2] | ((uint32_t)ov[3] << 16);
  op.z = (uint32_t)ov[4] | ((uint32_t)ov[5] << 16);
  op.w = (uint32_t)ov[6] | ((uint32_t)ov[7] << 16);
  *(uint4*)(OS + base + e0) = op;
}

extern "C" void kernel_launch(void* const* d_in, const int* in_sizes, int n_in,
                              void* d_out, int out_size, void* d_ws, size_t ws_size,
                              hipStream_t stream) {
  (void)in_sizes; (void)n_in; (void)out_size;
  const float* x   = (const float*)d_in[0];
  const float* w_i = (const float*)d_in[1];
  const float* w_f = (const float*)d_in[2];
  const float* w_g = (const float*)d_in[3];
  const float* w_o = (const float*)d_in[4];
  const float* s_i = (const float*)d_in[5];
  const float* s_f = (const float*)d_in[6];
  const float* s_g = (const float*)d_in[7];
  const float* s_o = (const float*)d_in[8];
  const float* gnw = (const float*)d_in[9];
  float* out = (float*)d_out;

  const size_t MB = 1024 * 1024;
  const size_t NEED = 88 * MB;
  if (ws_size < NEED) {
    diag_ws<<<MROWS * DIM / 2048, 256, 0, stream>>>(out, (float)(ws_size / MB));
    return;
  }

  uint8_t* ws = (uint8_t*)d_ws;
  u16* XB = (u16*)(ws);                    // [0, 32M)
  u16* WT = (u16*)(ws + 32 * MB);          // [32M, 56M), dead after gemm_gates
  u16* Ib = (u16*)(ws + 56 * MB);          // [56M, 88M)
  float* Pc = (float*)(ws + 32 * MB);      // overlay dead WT: 1 MB
  float* Sc = (float*)(ws + 33 * MB);      // 1 MB
  u16* WOB = (u16*)(ws + 34 * MB);         // 8 MB, written after scan
  u16* Hb  = XB;                           // alias: XB dead after gemm_gates
  u16* OS  = Ib;                           // alias: Ib dead after scan_phase2
  u16* Gb = (u16*)d_out;                   // d_out scratch [0,32M): swish-gate
  u16* Fb = (u16*)((uint8_t*)d_out + 32 * MB);  // [32M,64M): sigmoid f

  prep_x<<<MROWS * DIM / 1024, 256, 0, stream>>>(x, XB);
  prep_wT<<<dim3(DIM / 32, DIM / 32, 3), dim3(32, 8, 1), 0, stream>>>(w_i, w_f, w_g, WT);
  gemm_gates8<<<768, 512, 0, stream>>>(XB, WT, s_i, s_f, s_g, gnw, s_o, Ib, Fb, Gb);
  scan_phase1<<<dim3(DIM / 512, NCH, BATCH), 256, 0, stream>>>(Fb, Ib, Pc, Sc);
  scan_phase2<<<dim3(DIM / 512, NCH, BATCH), 256, 0, stream>>>(Fb, Ib, Pc, Sc, Hb);
  prep_wo<<<DIM * DIM / 1024, 256, 0, stream>>>(w_o, WOB);
  rms_gate<<<MROWS, 256, 0, stream>>>(Hb, Gb, OS);
  gemm_out8<<<256, 512, 0, stream>>>(OS, WOB, out);
}